// Round 1
// baseline (1300.157 us; speedup 1.0000x reference)
//
#include <hip/hip_runtime.h>
#include <hip/hip_bf16.h>

#define N_NODES 100000
#define N_EDGES 1600000
#define F_IN    256
#define F_OUT   64
#define N_REL   2
#define N_BASES 30
#define W_COLS  192   // cols 0..63 -> W[rel0], 64..127 -> W[rel1], 128..191 -> root

// ---------------------------------------------------------------------------
// Kernel 0: w_all[k][c] = sum_b att[r][b]*basis[b][k][f]  (c<128), root (c>=128)
// ---------------------------------------------------------------------------
__global__ __launch_bounds__(256) void wcomp_kernel(
    const float* __restrict__ att, const float* __restrict__ basis,
    const float* __restrict__ root, float* __restrict__ w_all)
{
    int idx = blockIdx.x * 256 + threadIdx.x;          // 0..49151
    if (idx >= F_IN * W_COLS) return;
    int k = idx / W_COLS;
    int c = idx - k * W_COLS;
    int m = c >> 6;          // 0,1 = relation, 2 = root
    int f = c & 63;
    if (m == 2) { w_all[idx] = root[k * F_OUT + f]; return; }
    float s = 0.f;
    #pragma unroll
    for (int b = 0; b < N_BASES; ++b)
        s += att[m * N_BASES + b] * basis[((long)b * F_IN + k) * F_OUT + f];
    w_all[idx] = s;
}

// ---------------------------------------------------------------------------
// Kernel 1: fused GEMM  [100000,256] x [256,192]
//   cols 0..127  -> h[r][n][f]   (workspace)
//   cols 128..191-> out[n][f] = x@root + bias   (written straight to d_out)
// 64 rows per block; x tile staged in LDS; 256 thr = 4 rowgroups x 64 cols.
// ---------------------------------------------------------------------------
__global__ __launch_bounds__(256) void gemm_kernel(
    const float* __restrict__ x, const float* __restrict__ w_all,
    const float* __restrict__ bias, float* __restrict__ h,
    float* __restrict__ out)
{
    __shared__ float xs[64][68];   // 68: row stride 272B (16B-aligned), modest conflicts on write only
    const int c  = threadIdx.x & 63;
    const int rg = threadIdx.x >> 6;           // 0..3
    const long row0 = (long)blockIdx.x * 64;

    float acc[16][3];
    #pragma unroll
    for (int i = 0; i < 16; ++i)
        #pragma unroll
        for (int m = 0; m < 3; ++m) acc[i][m] = 0.f;

    for (int k0 = 0; k0 < F_IN; k0 += 64) {
        __syncthreads();   // protect previous chunk's reads
        // stage x[row0..+63][k0..+63]: 1024 float4, 4 per thread
        #pragma unroll
        for (int j = 0; j < 4; ++j) {
            int t  = threadIdx.x + j * 256;    // 0..1023
            int r  = t >> 4;                   // row within tile
            int kq = t & 15;                   // float4 within row
            long row = row0 + r;
            if (row >= N_NODES) row = N_NODES - 1;   // clamp (dup read, harmless)
            float4 v = *reinterpret_cast<const float4*>(&x[row * F_IN + k0 + kq * 4]);
            *reinterpret_cast<float4*>(&xs[r][kq * 4]) = v;
        }
        __syncthreads();

        #pragma unroll
        for (int kk = 0; kk < 64; kk += 4) {
            float w4[3][4];
            #pragma unroll
            for (int m = 0; m < 3; ++m)
                #pragma unroll
                for (int q = 0; q < 4; ++q)
                    w4[m][q] = w_all[(k0 + kk + q) * W_COLS + m * 64 + c];
            #pragma unroll
            for (int i = 0; i < 16; ++i) {
                float4 xv = *reinterpret_cast<const float4*>(&xs[rg * 16 + i][kk]);
                #pragma unroll
                for (int m = 0; m < 3; ++m) {
                    acc[i][m] = fmaf(xv.x, w4[m][0], acc[i][m]);
                    acc[i][m] = fmaf(xv.y, w4[m][1], acc[i][m]);
                    acc[i][m] = fmaf(xv.z, w4[m][2], acc[i][m]);
                    acc[i][m] = fmaf(xv.w, w4[m][3], acc[i][m]);
                }
            }
        }
    }

    const float bc = bias[c];
    const long rbase = row0 + rg * 16;
    #pragma unroll
    for (int i = 0; i < 16; ++i) {
        long row = rbase + i;
        if (row < N_NODES) {
            h[row * F_OUT + c]                           = acc[i][0];
            h[((long)N_NODES + row) * F_OUT + c]         = acc[i][1];
            out[row * F_OUT + c]                         = acc[i][2] + bc;
        }
    }
}

// ---------------------------------------------------------------------------
// Kernel 2: edge scatter.  One wave per edge: lane l handles feature l.
// ---------------------------------------------------------------------------
__global__ __launch_bounds__(256) void edge_kernel(
    const int* __restrict__ edge_index, const int* __restrict__ edge_type,
    const float* __restrict__ h, float* __restrict__ agg, float* __restrict__ cnt)
{
    const int lane = threadIdx.x & 63;
    int wid = blockIdx.x * 4 + (threadIdx.x >> 6);
    const int nwaves = gridDim.x * 4;
    for (int e = wid; e < N_EDGES; e += nwaves) {
        int src = edge_index[e];
        int dst = edge_index[N_EDGES + e];
        int et  = edge_type[e];
        float v = h[((long)et * N_NODES + src) * F_OUT + lane];
        atomicAdd(&agg[(long)dst * F_OUT + lane], v);
        if (lane == 0) atomicAdd(&cnt[dst], 1.0f);
    }
}

// ---------------------------------------------------------------------------
// Kernel 3: out += agg / max(cnt,1)
// ---------------------------------------------------------------------------
__global__ __launch_bounds__(256) void fin_kernel(
    const float* __restrict__ agg, const float* __restrict__ cnt,
    float* __restrict__ out)
{
    int idx = blockIdx.x * 256 + threadIdx.x;       // float4 units
    if (idx >= N_NODES * F_OUT / 4) return;
    int n = idx >> 4;                                // 16 float4 per node
    float rinv = 1.0f / fmaxf(cnt[n], 1.0f);
    float4 a = *reinterpret_cast<const float4*>(&agg[(long)idx * 4]);
    float4 o = *reinterpret_cast<float4*>(&out[(long)idx * 4]);
    o.x = fmaf(a.x, rinv, o.x);
    o.y = fmaf(a.y, rinv, o.y);
    o.z = fmaf(a.z, rinv, o.z);
    o.w = fmaf(a.w, rinv, o.w);
    *reinterpret_cast<float4*>(&out[(long)idx * 4]) = o;
}

// ---------------------------------------------------------------------------
extern "C" void kernel_launch(void* const* d_in, const int* in_sizes, int n_in,
                              void* d_out, int out_size, void* d_ws, size_t ws_size,
                              hipStream_t stream)
{
    const float* x          = (const float*)d_in[0];
    const int*   edge_index = (const int*)  d_in[1];
    const int*   edge_type  = (const int*)  d_in[2];
    const float* basis      = (const float*)d_in[3];
    const float* att        = (const float*)d_in[4];
    const float* root       = (const float*)d_in[5];
    const float* bias       = (const float*)d_in[6];
    float* out = (float*)d_out;

    float* ws    = (float*)d_ws;
    float* w_all = ws;                                        // 49152
    float* h     = w_all + (size_t)F_IN * W_COLS;             // 2*100000*64
    float* agg   = h + (size_t)N_REL * N_NODES * F_OUT;       // 100000*64
    float* cnt   = agg + (size_t)N_NODES * F_OUT;             // 100000

    // zero agg + cnt (contiguous)
    hipMemsetAsync(agg, 0, ((size_t)N_NODES * F_OUT + N_NODES) * sizeof(float), stream);

    wcomp_kernel<<<192, 256, 0, stream>>>(att, basis, root, w_all);

    gemm_kernel<<<(N_NODES + 63) / 64, 256, 0, stream>>>(x, w_all, bias, h, out);

    edge_kernel<<<1024, 256, 0, stream>>>(edge_index, edge_type, h, agg, cnt);

    fin_kernel<<<(N_NODES * F_OUT / 4 + 255) / 256, 256, 0, stream>>>(agg, cnt, out);
}

// Round 5
// 743.641 us; speedup vs baseline: 1.7484x; 1.7484x over previous
//
#include <hip/hip_runtime.h>
#include <hip/hip_bf16.h>

#define N_NODES 100000
#define N_EDGES 1600000
#define F_IN    256
#define F_OUT   64
#define N_REL   2
#define N_BASES 30
#define W_COLS  192   // cols 0..63 -> W[rel0], 64..127 -> W[rel1], 128..191 -> root
#define SCAN_BS 512
#define N_SBLK  ((N_NODES + SCAN_BS - 1) / SCAN_BS)   // 196

// ---------------------------------------------------------------------------
// Kernel 0: w_all[k][c] = sum_b att[r][b]*basis[b][k][f]  (c<128), root (c>=128)
// ---------------------------------------------------------------------------
__global__ __launch_bounds__(256) void wcomp_kernel(
    const float* __restrict__ att, const float* __restrict__ basis,
    const float* __restrict__ root, float* __restrict__ w_all)
{
    int idx = blockIdx.x * 256 + threadIdx.x;          // 0..49151
    if (idx >= F_IN * W_COLS) return;
    int k = idx / W_COLS;
    int c = idx - k * W_COLS;
    int m = c >> 6;          // 0,1 = relation, 2 = root
    int f = c & 63;
    if (m == 2) { w_all[idx] = root[k * F_OUT + f]; return; }
    float s = 0.f;
    #pragma unroll
    for (int b = 0; b < N_BASES; ++b)
        s += att[m * N_BASES + b] * basis[((long)b * F_IN + k) * F_OUT + f];
    w_all[idx] = s;
}

// ---------------------------------------------------------------------------
// Kernel 1: fused GEMM [100000,256]x[256,192]. No LDS, no barriers.
// Wave owns 16 rows; x addresses wave-uniform (scalar path); w lane-coalesced.
// ---------------------------------------------------------------------------
__global__ __launch_bounds__(256) void gemm_kernel(
    const float* __restrict__ x, const float* __restrict__ w_all,
    const float* __restrict__ bias, float* __restrict__ h,
    float* __restrict__ out)
{
    const int lane = threadIdx.x & 63;
    const int wv   = __builtin_amdgcn_readfirstlane(threadIdx.x >> 6);
    const long row0 = (long)blockIdx.x * 64 + wv * 16;
    if (row0 >= N_NODES) return;     // 100000 % 16 == 0: waves are all-or-nothing

    float acc[16][3];
    #pragma unroll
    for (int i = 0; i < 16; ++i)
        #pragma unroll
        for (int m = 0; m < 3; ++m) acc[i][m] = 0.f;

    const float* xp = x + row0 * F_IN;

    #pragma unroll 2
    for (int k0 = 0; k0 < F_IN; k0 += 4) {
        float w4[3][4];
        #pragma unroll
        for (int m = 0; m < 3; ++m)
            #pragma unroll
            for (int q = 0; q < 4; ++q)
                w4[m][q] = w_all[(k0 + q) * W_COLS + m * 64 + lane];
        #pragma unroll
        for (int i = 0; i < 16; ++i) {
            float4 xv = *reinterpret_cast<const float4*>(xp + (long)i * F_IN + k0);
            #pragma unroll
            for (int m = 0; m < 3; ++m) {
                acc[i][m] = fmaf(xv.x, w4[m][0], acc[i][m]);
                acc[i][m] = fmaf(xv.y, w4[m][1], acc[i][m]);
                acc[i][m] = fmaf(xv.z, w4[m][2], acc[i][m]);
                acc[i][m] = fmaf(xv.w, w4[m][3], acc[i][m]);
            }
        }
    }

    const float bc = bias[lane];
    #pragma unroll
    for (int i = 0; i < 16; ++i) {
        long row = row0 + i;
        h[row * F_OUT + lane]                    = acc[i][0];
        h[((long)N_NODES + row) * F_OUT + lane]  = acc[i][1];
        out[row * F_OUT + lane]                  = acc[i][2] + bc;
    }
}

// ---------------------------------------------------------------------------
// Kernel 2: histogram of dst (also provides mean denominator)
// ---------------------------------------------------------------------------
__global__ __launch_bounds__(256) void hist_kernel(
    const int* __restrict__ edge_index, int* __restrict__ hist)
{
    int e = blockIdx.x * 256 + threadIdx.x;
    if (e >= N_EDGES) return;
    atomicAdd(&hist[edge_index[N_EDGES + e]], 1);
}

// ---------------------------------------------------------------------------
// Kernel 3a: per-block exclusive scan of hist (block=512) + block sums
// ---------------------------------------------------------------------------
__global__ __launch_bounds__(SCAN_BS) void scanA_kernel(
    const int* __restrict__ hist, int* __restrict__ offs, int* __restrict__ bsum)
{
    __shared__ int s[SCAN_BS];
    const int t = threadIdx.x;
    const int i = blockIdx.x * SCAN_BS + t;
    int v = (i < N_NODES) ? hist[i] : 0;
    s[t] = v;
    __syncthreads();
    #pragma unroll
    for (int off = 1; off < SCAN_BS; off <<= 1) {
        int y = (t >= off) ? s[t - off] : 0;
        __syncthreads();
        if (t >= off) s[t] += y;
        __syncthreads();
    }
    if (i < N_NODES) offs[i] = s[t] - v;          // exclusive
    if (t == SCAN_BS - 1) bsum[blockIdx.x] = s[t];
}

// ---------------------------------------------------------------------------
// Kernel 3b: scan of the 196 block sums (single block)
// ---------------------------------------------------------------------------
__global__ __launch_bounds__(256) void scanB_kernel(
    const int* __restrict__ bsum, int* __restrict__ bpre)
{
    __shared__ int s[256];
    const int t = threadIdx.x;
    int v = (t < N_SBLK) ? bsum[t] : 0;
    s[t] = v;
    __syncthreads();
    #pragma unroll
    for (int off = 1; off < 256; off <<= 1) {
        int y = (t >= off) ? s[t - off] : 0;
        __syncthreads();
        if (t >= off) s[t] += y;
        __syncthreads();
    }
    if (t < N_SBLK) bpre[t] = s[t] - v;           // exclusive
}

// ---------------------------------------------------------------------------
// Kernel 4: bucket edges by dst -> elist[pos] = src | (et<<20)
// ---------------------------------------------------------------------------
__global__ __launch_bounds__(256) void pass2_kernel(
    const int* __restrict__ edge_index, const int* __restrict__ edge_type,
    const int* __restrict__ offs, const int* __restrict__ bpre,
    int* __restrict__ cur, int* __restrict__ elist)
{
    int e = blockIdx.x * 256 + threadIdx.x;
    if (e >= N_EDGES) return;
    int src = edge_index[e];
    int dst = edge_index[N_EDGES + e];
    int et  = edge_type[e];
    int pos = offs[dst] + bpre[dst >> 9] + atomicAdd(&cur[dst], 1);
    elist[pos] = src | (et << 20);
}

// ---------------------------------------------------------------------------
// Kernel 5: per-node gather + mean, fused with out += (out holds x@root+bias)
// One wave per node; lane = feature.
// ---------------------------------------------------------------------------
__global__ __launch_bounds__(256) void gather_kernel(
    const int* __restrict__ hist, const int* __restrict__ offs,
    const int* __restrict__ bpre, const int* __restrict__ elist,
    const float* __restrict__ h, float* __restrict__ out)
{
    const int lane = threadIdx.x & 63;
    const int nid  = blockIdx.x * 4 + (threadIdx.x >> 6);
    if (nid >= N_NODES) return;
    const int cnt  = hist[nid];
    const int base = offs[nid] + bpre[nid >> 9];

    float acc = 0.f;
    int j = 0;
    for (; j + 4 <= cnt; j += 4) {
        int e0 = elist[base + j];
        int e1 = elist[base + j + 1];
        int e2 = elist[base + j + 2];
        int e3 = elist[base + j + 3];
        float v0 = h[((long)(e0 >> 20) * N_NODES + (e0 & 0xFFFFF)) * F_OUT + lane];
        float v1 = h[((long)(e1 >> 20) * N_NODES + (e1 & 0xFFFFF)) * F_OUT + lane];
        float v2 = h[((long)(e2 >> 20) * N_NODES + (e2 & 0xFFFFF)) * F_OUT + lane];
        float v3 = h[((long)(e3 >> 20) * N_NODES + (e3 & 0xFFFFF)) * F_OUT + lane];
        acc += v0; acc += v1; acc += v2; acc += v3;
    }
    for (; j < cnt; ++j) {
        int e = elist[base + j];
        acc += h[((long)(e >> 20) * N_NODES + (e & 0xFFFFF)) * F_OUT + lane];
    }
    float inv = 1.0f / fmaxf((float)cnt, 1.0f);
    out[(long)nid * F_OUT + lane] += acc * inv;
}

// ---------------------------------------------------------------------------
extern "C" void kernel_launch(void* const* d_in, const int* in_sizes, int n_in,
                              void* d_out, int out_size, void* d_ws, size_t ws_size,
                              hipStream_t stream)
{
    const float* x          = (const float*)d_in[0];
    const int*   edge_index = (const int*)  d_in[1];
    const int*   edge_type  = (const int*)  d_in[2];
    const float* basis      = (const float*)d_in[3];
    const float* att        = (const float*)d_in[4];
    const float* root       = (const float*)d_in[5];
    const float* bias       = (const float*)d_in[6];
    float* out = (float*)d_out;

    char* ws = (char*)d_ws;
    size_t off = 0;
    float* w_all = (float*)(ws + off); off += (size_t)F_IN * W_COLS * 4;
    float* h     = (float*)(ws + off); off += (size_t)N_REL * N_NODES * F_OUT * 4;
    int*   hist  = (int*)  (ws + off); off += (size_t)N_NODES * 4;
    int*   cur   = (int*)  (ws + off); off += (size_t)N_NODES * 4;
    int*   offs  = (int*)  (ws + off); off += (size_t)N_NODES * 4;
    int*   bsum  = (int*)  (ws + off); off += (size_t)N_SBLK * 4;
    int*   bpre  = (int*)  (ws + off); off += (size_t)N_SBLK * 4;
    int*   elist = (int*)  (ws + off); off += (size_t)N_EDGES * 4;

    // zero hist + cur (contiguous)
    hipMemsetAsync(hist, 0, (size_t)2 * N_NODES * 4, stream);

    wcomp_kernel<<<192, 256, 0, stream>>>(att, basis, root, w_all);

    gemm_kernel<<<(N_NODES + 63) / 64, 256, 0, stream>>>(x, w_all, bias, h, out);

    hist_kernel<<<(N_EDGES + 255) / 256, 256, 0, stream>>>(edge_index, hist);

    scanA_kernel<<<N_SBLK, SCAN_BS, 0, stream>>>(hist, offs, bsum);

    scanB_kernel<<<1, 256, 0, stream>>>(bsum, bpre);

    pass2_kernel<<<(N_EDGES + 255) / 256, 256, 0, stream>>>(
        edge_index, edge_type, offs, bpre, cur, elist);

    gather_kernel<<<(N_NODES + 3) / 4, 256, 0, stream>>>(
        hist, offs, bpre, elist, h, out);
}

// Round 6
// 466.746 us; speedup vs baseline: 2.7856x; 1.5932x over previous
//
#include <hip/hip_runtime.h>
#include <hip/hip_bf16.h>

#define N_NODES 100000
#define N_EDGES 1600000
#define F_IN    256
#define F_OUT   64
#define N_REL   2
#define N_BASES 30
#define SCAN_BS 512
#define N_SBLK  ((N_NODES + SCAN_BS - 1) / SCAN_BS)   // 196
#define N_NT    12          // 192 output cols / 16
#define N_KS    8           // 256 k / 32

typedef __attribute__((ext_vector_type(8))) short bf16x8;
typedef __attribute__((ext_vector_type(4))) float f32x4;

__device__ inline unsigned short f2bf(float f) {            // RTNE
    unsigned u = __float_as_uint(f);
    unsigned r = u + 0x7FFF + ((u >> 16) & 1);
    return (unsigned short)(r >> 16);
}
__device__ inline float bf2f(unsigned short b) {
    return __uint_as_float(((unsigned)b) << 16);
}

// ---------------------------------------------------------------------------
// Kernel 0: build B-operand fragments of W = [att@basis | att@basis | root]
// in bf16 hi/lo split, laid out so gemm lane loads one dwordx4 per frag.
// idx = (ks*12 + nt)*64 + lane ; value i: w[k = ks*32+(lane>>4)*8+i][c = nt*16+(lane&15)]
// ---------------------------------------------------------------------------
__global__ __launch_bounds__(256) void wcomp_kernel(
    const float* __restrict__ att, const float* __restrict__ basis,
    const float* __restrict__ root,
    unsigned short* __restrict__ wb_hi, unsigned short* __restrict__ wb_lo)
{
    int idx = blockIdx.x * 256 + threadIdx.x;
    if (idx >= N_KS * N_NT * 64) return;
    const int lane  = idx & 63;
    const int nt    = (idx >> 6) % N_NT;
    const int ks    = idx / (N_NT * 64);
    const int c     = nt * 16 + (lane & 15);      // 0..191
    const int kbase = ks * 32 + (lane >> 4) * 8;
    const int m     = c >> 6;                     // 0,1 rel ; 2 root
    const int f     = c & 63;

    bf16x8 hi, lo;
    #pragma unroll
    for (int i = 0; i < 8; ++i) {
        int k = kbase + i;
        float v;
        if (m == 2) {
            v = root[k * F_OUT + f];
        } else {
            v = 0.f;
            #pragma unroll
            for (int b = 0; b < N_BASES; ++b)
                v += att[m * N_BASES + b] * basis[((long)b * F_IN + k) * F_OUT + f];
        }
        unsigned short h = f2bf(v);
        unsigned short l = f2bf(v - bf2f(h));
        hi[i] = (short)h;
        lo[i] = (short)l;
    }
    *reinterpret_cast<bf16x8*>(wb_hi + (long)idx * 8) = hi;
    *reinterpret_cast<bf16x8*>(wb_lo + (long)idx * 8) = lo;
}

// ---------------------------------------------------------------------------
// Kernel 1: MFMA GEMM [100000,256]x[256,192], bf16 2-term split (hi/lo),
// C = Ahi*Bhi + Alo*Bhi + Ahi*Blo accumulated in fp32.
// Wave owns 32 rows (2 M-tiles) x 192 cols (12 N-tiles). Barrier-free.
//   cols 0..127  -> h[rel][n][f], cols 128..191 -> out = x@root + bias
// ---------------------------------------------------------------------------
__global__ __launch_bounds__(256) void gemm_kernel(
    const float* __restrict__ x,
    const unsigned short* __restrict__ wb_hi,
    const unsigned short* __restrict__ wb_lo,
    const float* __restrict__ bias,
    float* __restrict__ h, float* __restrict__ out)
{
    const int lane = threadIdx.x & 63;
    const int wv   = threadIdx.x >> 6;
    const long row0 = (long)blockIdx.x * 128 + wv * 32;
    if (row0 >= N_NODES) return;          // 100000 % 32 == 0: all-or-nothing

    const int mrow = lane & 15;           // A row within 16-tile
    const int kgrp = lane >> 4;           // 0..3, k-subgroup of 8

    f32x4 acc[2][N_NT];
    #pragma unroll
    for (int mt = 0; mt < 2; ++mt)
        #pragma unroll
        for (int nt = 0; nt < N_NT; ++nt)
            acc[mt][nt] = (f32x4){0.f, 0.f, 0.f, 0.f};

    const float* xp = x + (row0 + mrow) * F_IN + kgrp * 8;

    for (int ks = 0; ks < N_KS; ++ks) {
        // ---- A fragments: 8 consecutive fp32 per lane -> bf16 hi/lo
        bf16x8 ah[2], al[2];
        #pragma unroll
        for (int mt = 0; mt < 2; ++mt) {
            const float* p = xp + (long)mt * 16 * F_IN + ks * 32;
            float4 f0 = *reinterpret_cast<const float4*>(p);
            float4 f1 = *reinterpret_cast<const float4*>(p + 4);
            float fv[8] = {f0.x, f0.y, f0.z, f0.w, f1.x, f1.y, f1.z, f1.w};
            #pragma unroll
            for (int i = 0; i < 8; ++i) {
                unsigned short hb = f2bf(fv[i]);
                ah[mt][i] = (short)hb;
                al[mt][i] = (short)f2bf(fv[i] - bf2f(hb));
            }
        }
        // ---- B fragments + MFMA
        const unsigned short* bh_base = wb_hi + ((long)(ks * N_NT) * 64 + lane) * 8;
        const unsigned short* bl_base = wb_lo + ((long)(ks * N_NT) * 64 + lane) * 8;
        #pragma unroll
        for (int nt = 0; nt < N_NT; ++nt) {
            bf16x8 bh = *reinterpret_cast<const bf16x8*>(bh_base + (long)nt * 64 * 8);
            bf16x8 bl = *reinterpret_cast<const bf16x8*>(bl_base + (long)nt * 64 * 8);
            #pragma unroll
            for (int mt = 0; mt < 2; ++mt) {
                acc[mt][nt] = __builtin_amdgcn_mfma_f32_16x16x32_bf16(ah[mt], bh, acc[mt][nt], 0, 0, 0);
                acc[mt][nt] = __builtin_amdgcn_mfma_f32_16x16x32_bf16(al[mt], bh, acc[mt][nt], 0, 0, 0);
                acc[mt][nt] = __builtin_amdgcn_mfma_f32_16x16x32_bf16(ah[mt], bl, acc[mt][nt], 0, 0, 0);
            }
        }
    }

    // ---- epilogue: D lane mapping col=lane&15, row=(lane>>4)*4+i
    const int ccol = lane & 15;
    const int rsub = (lane >> 4) * 4;
    #pragma unroll
    for (int mt = 0; mt < 2; ++mt) {
        #pragma unroll
        for (int nt = 0; nt < N_NT; ++nt) {
            const int rel = nt >> 2;                    // 0,1 -> h ; 2 -> out
            const int fc  = (nt & 3) * 16 + ccol;
            float badd = (rel == 2) ? bias[fc] : 0.f;
            #pragma unroll
            for (int i = 0; i < 4; ++i) {
                long row = row0 + mt * 16 + rsub + i;
                float v = acc[mt][nt][i] + badd;
                if (rel == 2) out[row * F_OUT + fc] = v;
                else          h[((long)rel * N_NODES + row) * F_OUT + fc] = v;
            }
        }
    }
}

// ---------------------------------------------------------------------------
// Kernel 2: histogram of dst (also provides mean denominator)
// ---------------------------------------------------------------------------
__global__ __launch_bounds__(256) void hist_kernel(
    const int* __restrict__ edge_index, int* __restrict__ hist)
{
    int e = blockIdx.x * 256 + threadIdx.x;
    if (e >= N_EDGES) return;
    atomicAdd(&hist[edge_index[N_EDGES + e]], 1);
}

// ---------------------------------------------------------------------------
// Kernel 3a: per-block exclusive scan of hist (block=512) + block sums
// ---------------------------------------------------------------------------
__global__ __launch_bounds__(SCAN_BS) void scanA_kernel(
    const int* __restrict__ hist, int* __restrict__ offs, int* __restrict__ bsum)
{
    __shared__ int s[SCAN_BS];
    const int t = threadIdx.x;
    const int i = blockIdx.x * SCAN_BS + t;
    int v = (i < N_NODES) ? hist[i] : 0;
    s[t] = v;
    __syncthreads();
    #pragma unroll
    for (int off = 1; off < SCAN_BS; off <<= 1) {
        int y = (t >= off) ? s[t - off] : 0;
        __syncthreads();
        if (t >= off) s[t] += y;
        __syncthreads();
    }
    if (i < N_NODES) offs[i] = s[t] - v;          // exclusive
    if (t == SCAN_BS - 1) bsum[blockIdx.x] = s[t];
}

// ---------------------------------------------------------------------------
// Kernel 3b: scan of the 196 block sums (single block)
// ---------------------------------------------------------------------------
__global__ __launch_bounds__(256) void scanB_kernel(
    const int* __restrict__ bsum, int* __restrict__ bpre)
{
    __shared__ int s[256];
    const int t = threadIdx.x;
    int v = (t < N_SBLK) ? bsum[t] : 0;
    s[t] = v;
    __syncthreads();
    #pragma unroll
    for (int off = 1; off < 256; off <<= 1) {
        int y = (t >= off) ? s[t - off] : 0;
        __syncthreads();
        if (t >= off) s[t] += y;
        __syncthreads();
    }
    if (t < N_SBLK) bpre[t] = s[t] - v;           // exclusive
}

// ---------------------------------------------------------------------------
// Kernel 4: bucket edges by dst -> elist[pos] = src | (et<<20)
// ---------------------------------------------------------------------------
__global__ __launch_bounds__(256) void pass2_kernel(
    const int* __restrict__ edge_index, const int* __restrict__ edge_type,
    const int* __restrict__ offs, const int* __restrict__ bpre,
    int* __restrict__ cur, int* __restrict__ elist)
{
    int e = blockIdx.x * 256 + threadIdx.x;
    if (e >= N_EDGES) return;
    int src = edge_index[e];
    int dst = edge_index[N_EDGES + e];
    int et  = edge_type[e];
    int pos = offs[dst] + bpre[dst >> 9] + atomicAdd(&cur[dst], 1);
    elist[pos] = src | (et << 20);
}

// ---------------------------------------------------------------------------
// Kernel 5: per-node gather + mean, fused with out += (out holds x@root+bias)
// One wave per node; lane = feature.
// ---------------------------------------------------------------------------
__global__ __launch_bounds__(256) void gather_kernel(
    const int* __restrict__ hist, const int* __restrict__ offs,
    const int* __restrict__ bpre, const int* __restrict__ elist,
    const float* __restrict__ h, float* __restrict__ out)
{
    const int lane = threadIdx.x & 63;
    const int nid  = blockIdx.x * 4 + (threadIdx.x >> 6);
    if (nid >= N_NODES) return;
    const int cnt  = hist[nid];
    const int base = offs[nid] + bpre[nid >> 9];

    float acc = 0.f;
    int j = 0;
    for (; j + 4 <= cnt; j += 4) {
        int e0 = elist[base + j];
        int e1 = elist[base + j + 1];
        int e2 = elist[base + j + 2];
        int e3 = elist[base + j + 3];
        float v0 = h[((long)(e0 >> 20) * N_NODES + (e0 & 0xFFFFF)) * F_OUT + lane];
        float v1 = h[((long)(e1 >> 20) * N_NODES + (e1 & 0xFFFFF)) * F_OUT + lane];
        float v2 = h[((long)(e2 >> 20) * N_NODES + (e2 & 0xFFFFF)) * F_OUT + lane];
        float v3 = h[((long)(e3 >> 20) * N_NODES + (e3 & 0xFFFFF)) * F_OUT + lane];
        acc += v0; acc += v1; acc += v2; acc += v3;
    }
    for (; j < cnt; ++j) {
        int e = elist[base + j];
        acc += h[((long)(e >> 20) * N_NODES + (e & 0xFFFFF)) * F_OUT + lane];
    }
    float inv = 1.0f / fmaxf((float)cnt, 1.0f);
    out[(long)nid * F_OUT + lane] += acc * inv;
}

// ---------------------------------------------------------------------------
extern "C" void kernel_launch(void* const* d_in, const int* in_sizes, int n_in,
                              void* d_out, int out_size, void* d_ws, size_t ws_size,
                              hipStream_t stream)
{
    const float* x          = (const float*)d_in[0];
    const int*   edge_index = (const int*)  d_in[1];
    const int*   edge_type  = (const int*)  d_in[2];
    const float* basis      = (const float*)d_in[3];
    const float* att        = (const float*)d_in[4];
    const float* root       = (const float*)d_in[5];
    const float* bias       = (const float*)d_in[6];
    float* out = (float*)d_out;

    char* ws = (char*)d_ws;
    size_t off = 0;
    unsigned short* wb_hi = (unsigned short*)(ws + off); off += (size_t)N_KS * N_NT * 64 * 8 * 2;
    unsigned short* wb_lo = (unsigned short*)(ws + off); off += (size_t)N_KS * N_NT * 64 * 8 * 2;
    float* h     = (float*)(ws + off); off += (size_t)N_REL * N_NODES * F_OUT * 4;
    int*   hist  = (int*)  (ws + off); off += (size_t)N_NODES * 4;
    int*   cur   = (int*)  (ws + off); off += (size_t)N_NODES * 4;
    int*   offs  = (int*)  (ws + off); off += (size_t)N_NODES * 4;
    int*   bsum  = (int*)  (ws + off); off += (size_t)N_SBLK * 4;
    int*   bpre  = (int*)  (ws + off); off += (size_t)N_SBLK * 4;
    int*   elist = (int*)  (ws + off); off += (size_t)N_EDGES * 4;

    // zero hist + cur (contiguous)
    hipMemsetAsync(hist, 0, (size_t)2 * N_NODES * 4, stream);

    wcomp_kernel<<<(N_KS * N_NT * 64 + 255) / 256, 256, 0, stream>>>(
        att, basis, root, wb_hi, wb_lo);

    gemm_kernel<<<(N_NODES + 127) / 128, 256, 0, stream>>>(
        x, wb_hi, wb_lo, bias, h, out);

    hist_kernel<<<(N_EDGES + 255) / 256, 256, 0, stream>>>(edge_index, hist);

    scanA_kernel<<<N_SBLK, SCAN_BS, 0, stream>>>(hist, offs, bsum);

    scanB_kernel<<<1, 256, 0, stream>>>(bsum, bpre);

    pass2_kernel<<<(N_EDGES + 255) / 256, 256, 0, stream>>>(
        edge_index, edge_type, offs, bpre, cur, elist);

    gather_kernel<<<(N_NODES + 3) / 4, 256, 0, stream>>>(
        hist, offs, bpre, elist, h, out);
}